// Round 12
// baseline (378.469 us; speedup 1.0000x reference)
//
#include <hip/hip_runtime.h>
#include <hip/hip_bf16.h>

#define N_NODES 50000
#define N_EDGES 800000
#define F_IN 1024
#define F_MID 256

typedef _Float16 f16;
typedef _Float16 f16x4 __attribute__((ext_vector_type(4)));
typedef _Float16 f16x8 __attribute__((ext_vector_type(8)));
typedef float f32x4 __attribute__((ext_vector_type(4)));

__device__ __forceinline__ void glds16(const f16* g, f16* l) {
    __builtin_amdgcn_global_load_lds(
        (const __attribute__((address_space(1))) unsigned int*)g,
        (__attribute__((address_space(3))) unsigned int*)l, 16, 0, 0);
}

// ---------------- threefry2x32 (JAX-exact, key=(0,42)); verified: bits = x0^x1, ctr=(0,f) ----------------
__device__ __forceinline__ void tf_round(unsigned &x0, unsigned &x1, int r) {
    x0 += x1;
    x1 = (x1 << r) | (x1 >> (32 - r));
    x1 ^= x0;
}

__device__ __forceinline__ int keep_mask(unsigned f) {
    const unsigned ks0 = 0u, ks1 = 42u;
    const unsigned ks2 = ks0 ^ ks1 ^ 0x1BD11BDAu;
    unsigned x0 = 0u + ks0;
    unsigned x1 = f + ks1;
    tf_round(x0,x1,13); tf_round(x0,x1,15); tf_round(x0,x1,26); tf_round(x0,x1,6);
    x0 += ks1; x1 += ks2 + 1u;
    tf_round(x0,x1,17); tf_round(x0,x1,29); tf_round(x0,x1,16); tf_round(x0,x1,24);
    x0 += ks2; x1 += ks0 + 2u;
    tf_round(x0,x1,13); tf_round(x0,x1,15); tf_round(x0,x1,26); tf_round(x0,x1,6);
    x0 += ks0; x1 += ks1 + 3u;
    tf_round(x0,x1,17); tf_round(x0,x1,29); tf_round(x0,x1,16); tf_round(x0,x1,24);
    x0 += ks1; x1 += ks2 + 4u;
    tf_round(x0,x1,13); tf_round(x0,x1,15); tf_round(x0,x1,26); tf_round(x0,x1,6);
    x0 += ks2; x1 += ks0 + 5u;
    return (((x0 ^ x1) >> 31) == 0u);
}

__device__ __forceinline__ int ld_src(const int* ei, int e, int is64) {
    return is64 ? ei[2 * e] : ei[e];
}
__device__ __forceinline__ int ld_dst(const int* ei, int e, int is64) {
    return is64 ? ei[2 * N_EDGES + 2 * e] : ei[N_EDGES + e];
}

// ---------------- prep: zero deg/cursor/counter, dtype-detect, cvt+transpose+swizzle W1 ----------------
__global__ __launch_bounds__(256) void k_prep(const float* __restrict__ W1, f16* __restrict__ W1T,
                                              const int* __restrict__ ei,
                                              int* deg, int* cursor, int* counter, int* flag) {
    const int tid = threadIdx.x;
    const int gid = blockIdx.x * 256 + tid;
    const int gstr = gridDim.x * 256;
    if (gid < N_NODES) { deg[gid] = 0; cursor[gid] = 0; }
    if (gid == 0) counter[0] = 0;
    if (blockIdx.x == 0) {
        if (tid == 0) flag[0] = 1;            // 1 = int64
        __syncthreads();
        int nz = 0;
        for (int k = tid; k < 1024; k += 256) nz |= (ei[2 * k + 1] != 0);
        if (nz) atomicAnd(flag, 0);
    }
    for (int i = gid; i < F_IN * F_MID; i += gstr) {
        int k = i >> 8, n = i & 255;          // W1 [1024][256]
        W1T[(size_t)n * F_IN + (k ^ ((n & 7) << 3))] = (f16)W1[i];
    }
}

__global__ __launch_bounds__(256) void k_rows(const int* __restrict__ deg, float* __restrict__ dinv,
                                              int* __restrict__ rowst, int* __restrict__ counter) {
    int i = blockIdx.x * 256 + threadIdx.x;
    if (i < N_NODES) {
        dinv[i] = rsqrtf((float)(deg[i] + 1));       // +1 self-loop
        rowst[i] = atomicAdd(counter, deg[i]);
    }
}

__global__ __launch_bounds__(256) void k_fill(const int* __restrict__ ei, const int* __restrict__ rowst,
                                              int* __restrict__ cursor, int* __restrict__ csr,
                                              const int* __restrict__ flag) {
    int e = blockIdx.x * 256 + threadIdx.x;
    int is64 = flag[0];
    if (e < N_EDGES) {
        int d = ld_dst(ei, e, is64);
        int pos = rowst[d] + atomicAdd(&cursor[d], 1);
        csr[pos] = ld_src(ei, e, is64);
    }
}

// ---------------- MFMA f16 GEMM: fat K-steps, single-buffered LDS, plain-barrier schedule ----------------
// C[M,Ntot] = A[M,K] @ BT[Ntot,K]^T.   BT pre-swizzled in global: kk = k ^ ((n&7)<<3).
// A16=0 (GEMM1): A f32, reg-staged (NT f32x4) -> cvt -> swizzled ds_write, single 16KB slot.
// A16=1 (GEMM2): A f16 pre-swizzled in global, FULL K panel glds'd once in prologue.
// B: single slot BN*BK, glds, re-filled between two __syncthreads (drain = built-in vmcnt(0)).
// C16: f16 out unscaled; else f32 + bias (LDS-transposed contiguous NT stores).
// Riders (blockIdx.x >= mainx, GEMM1 only): edge-degree count + W2 cvt+transpose+swizzle.
template<int BM, int BN, int TN, int K, int BK, bool A16, bool C16>
__global__ __launch_bounds__(TN) void k_mfma(const void* __restrict__ Ag,
                                             const f16* __restrict__ BTg,
                                             void* __restrict__ Cg,
                                             const float* __restrict__ bias,
                                             int M, int Ntot, int mainx,
                                             const int* __restrict__ ei, int* __restrict__ deg,
                                             const int* __restrict__ flag,
                                             const float* __restrict__ Wr, f16* __restrict__ WrT) {
    if ((int)blockIdx.x >= mainx) {
        const int str = (gridDim.x - mainx) * TN;
        const int t0 = (blockIdx.x - mainx) * TN + threadIdx.x;
        const int is64 = flag[0];
        for (int e = t0; e < N_EDGES; e += str)
            atomicAdd(&deg[ld_dst(ei, e, is64)], 1);
        for (int i = t0; i < F_MID * F_IN; i += str) {
            int k = i >> 10, n = i & 1023;    // Wr [256][1024]
            WrT[(size_t)n * F_MID + (k ^ ((n & 7) << 3))] = (f16)Wr[i];
        }
        return;
    }

    static_assert(BM == 64 && BN == 256 && TN == 512, "tile fixed");
    constexpr int NKT = K / BK;
    constexpr int NW = TN / 64;           // 8 waves
    constexpr int WTN = BN / NW;          // 32
    constexpr int FN = WTN / 16;          // 2
    constexpr int ALDS = A16 ? BM * K : BM * BK;     // halves
    constexpr int BLDS = BN * BK;                    // halves
    constexpr int SMEM_STG = (ALDS + BLDS) * 2;
    constexpr int LDC = BN + 8;
    constexpr int SMEM_EPI = BM * LDC * (C16 ? 2 : 4);
    constexpr int SMEM_SZ = SMEM_STG > SMEM_EPI ? SMEM_STG : SMEM_EPI;
    __shared__ __align__(16) char smem[SMEM_SZ];
    f16* As_ = (f16*)smem;
    f16* Bs_ = As_ + ALDS;

    const int tid = threadIdx.x, lane = tid & 63, wid = tid >> 6;
    const int l15 = lane & 15, g8 = (lane >> 4) * 8;
    const int row0 = blockIdx.x * BM, col0 = blockIdx.y * BN;

    // B staging: 1KB wave-chunks
    constexpr int BCH = BLDS / 512 / NW;
    auto gldsB = [&](int kt) {
        const int k0 = kt * BK;
        #pragma unroll
        for (int j = 0; j < BCH; ++j) {
            int ci = wid * BCH + j;
            int li = ci * 512 + lane * 8;
            int r = li / BK, c = li % BK;
            glds16(&BTg[(size_t)(col0 + r) * K + k0 + c], &Bs_[ci * 512]);
        }
    };

    // A staging (f32 path): thread owns 16 consecutive halves of one row
    const int ar = tid >> 3;              // 64 rows x 8 thr
    const int ac = (tid & 7) * 16;
    f32x4 av[4];
    auto loadA = [&](int kt) {
        const float* A = (const float*)Ag;
        const int gr = row0 + ar;
        const int k0 = kt * BK;
        if (gr < M) {
            #pragma unroll
            for (int u = 0; u < 4; ++u)
                av[u] = __builtin_nontemporal_load((const f32x4*)&A[(size_t)gr * K + k0 + ac + u * 4]);
        } else {
            #pragma unroll
            for (int u = 0; u < 4; ++u) av[u] = (f32x4){};
        }
    };
    auto awrite = [&]() {
        f16x4 a0 = __builtin_convertvector(av[0], f16x4);
        f16x4 a1 = __builtin_convertvector(av[1], f16x4);
        f16x4 a2 = __builtin_convertvector(av[2], f16x4);
        f16x4 a3 = __builtin_convertvector(av[3], f16x4);
        f16x8 lo = { a0[0],a0[1],a0[2],a0[3], a1[0],a1[1],a1[2],a1[3] };
        f16x8 hi = { a2[0],a2[1],a2[2],a2[3], a3[0],a3[1],a3[2],a3[3] };
        const int sw = (ar & 7) << 3;
        *(f16x8*)&As_[ar * BK + (ac ^ sw)] = lo;
        *(f16x8*)&As_[ar * BK + ((ac + 8) ^ sw)] = hi;
    };

    f32x4 acc[4][FN] = {};

    // ---- prologue ----
    if constexpr (A16) {
        constexpr int ACH = ALDS / 512 / NW;
        #pragma unroll
        for (int j = 0; j < ACH; ++j) {
            int ci = wid * ACH + j;
            int li = ci * 512 + lane * 8;
            int r = li / K, c = li % K;
            glds16(&((const f16*)Ag)[(size_t)(row0 + r) * K + c], &As_[ci * 512]);
        }
    } else {
        loadA(0);
        awrite();
    }
    gldsB(0);
    __syncthreads();

    // ---- K loop: compute / barrier / refill / barrier ----
    #pragma unroll
    for (int kt = 0; kt < NKT; ++kt) {
        if constexpr (!A16) { if (kt + 1 < NKT) loadA(kt + 1); }
        {
            constexpr int ALD = A16 ? K : BK;     // A LDS row pitch (halves)
            const int kbase = A16 ? kt * BK : 0;
            #pragma unroll
            for (int ks = 0; ks < BK / 32; ++ks) {
                const int clA = kbase + ks * 32 + g8;
                const int clB = ks * 32 + g8;
                f16x8 af[4], bf[FN];
                #pragma unroll
                for (int m = 0; m < 4; ++m) {
                    int r = m * 16 + l15;
                    af[m] = *(const f16x8*)&As_[r * ALD + (clA ^ ((r & 7) << 3))];
                }
                #pragma unroll
                for (int n = 0; n < FN; ++n) {
                    int r = wid * WTN + n * 16 + l15;
                    bf[n] = *(const f16x8*)&Bs_[r * BK + (clB ^ ((r & 7) << 3))];
                }
                #pragma unroll
                for (int m = 0; m < 4; ++m)
                    #pragma unroll
                    for (int n = 0; n < FN; ++n)
                        acc[m][n] = __builtin_amdgcn_mfma_f32_16x16x32_f16(af[m], bf[n], acc[m][n], 0, 0, 0);
            }
        }
        __syncthreads();                          // all waves done reading A(kt)/B(kt)
        if (kt + 1 < NKT) {
            if constexpr (!A16) awrite();         // refill A slot (safe: past barrier)
            gldsB(kt + 1);                        // refill B slot
            __syncthreads();                      // built-in vmcnt(0)+lgkmcnt(0): tile ready
        }
    }

    // ---- epilogue: acc -> LDS (stride LDC) -> contiguous vector stores ----
    // C/D frag mapping: col=lane&15, row=(lane>>4)*4+reg
    if constexpr (C16) {
        f16* CT = (f16*)smem;
        #pragma unroll
        for (int m = 0; m < 4; ++m)
            #pragma unroll
            for (int j = 0; j < 4; ++j) {
                const int rl = m * 16 + (lane >> 4) * 4 + j;
                #pragma unroll
                for (int n = 0; n < FN; ++n)
                    CT[rl * LDC + wid * WTN + n * 16 + l15] = (f16)acc[m][n][j];
            }
        __syncthreads();
        f16* C = (f16*)Cg;
        constexpr int NCH = BM * BN / 8;
        #pragma unroll
        for (int ci = tid; ci < NCH; ci += TN) {
            const int r = ci / (BN / 8), c = (ci % (BN / 8)) * 8;
            const int gr = row0 + r;
            if (gr < M) {
                f16x8 v = *(const f16x8*)&CT[r * LDC + c];
                *(f16x8*)&C[(size_t)gr * Ntot + col0 + c] = v;
            }
        }
    } else {
        float* CT = (float*)smem;
        #pragma unroll
        for (int m = 0; m < 4; ++m)
            #pragma unroll
            for (int j = 0; j < 4; ++j) {
                const int rl = m * 16 + (lane >> 4) * 4 + j;
                #pragma unroll
                for (int n = 0; n < FN; ++n)
                    CT[rl * LDC + wid * WTN + n * 16 + l15] = acc[m][n][j];
            }
        __syncthreads();
        float* C = (float*)Cg;
        constexpr int NCH = BM * BN / 4;
        #pragma unroll
        for (int ci = tid; ci < NCH; ci += TN) {
            const int r = ci / (BN / 4), c = (ci % (BN / 4)) * 4;
            const int gr = row0 + r;
            if (gr < M) {
                f32x4 v = *(const f32x4*)&CT[r * LDC + c];
                v += *(const f32x4*)&bias[col0 + c];
                __builtin_nontemporal_store(v, (f32x4*)&C[(size_t)gr * Ntot + col0 + c]);
            }
        }
    }
}

// ---------------- aggregation (wave per row, unroll-4 gather) — R10 verbatim ----------------
// SCALED_IN=1: rows carry dinv[src] -> acc = hin[row] + sum hin[s]
// SCALED_IN=0: unscaled             -> acc = dinv[row]*hin[row] + sum dinv[s]*hin[s]
// Then *= dinv[row].  POST: +b1, relu, dropout, *dinv[row].  SWZ: write col ^ ((row&7)<<3).
template<int POST, int SWZ, int SCALED_IN>
__global__ __launch_bounds__(256) void k_agg16(const f16* __restrict__ hin,
                                               f16* __restrict__ hout,
                                               const int* __restrict__ csr,
                                               const int* __restrict__ rowst,
                                               const int* __restrict__ deg,
                                               const float* __restrict__ dinv,
                                               const float* __restrict__ bias) {
    const int wid = threadIdx.x >> 6;
    const int lane = threadIdx.x & 63;
    const int row = blockIdx.x * 4 + wid;
    const int start = rowst[row];
    const int cnt = deg[row];
    const int ch = lane * 4;
    const float di = dinv[row];

    f32x4 acc = __builtin_convertvector(*(const f16x4*)&hin[(size_t)row * F_MID + ch], f32x4);
    if (!SCALED_IN) acc *= di;
    int k = 0;
    for (; k + 4 <= cnt; k += 4) {
        const int s0 = csr[start + k], s1 = csr[start + k + 1];
        const int s2 = csr[start + k + 2], s3 = csr[start + k + 3];
        f16x4 v0 = *(const f16x4*)&hin[(size_t)s0 * F_MID + ch];
        f16x4 v1 = *(const f16x4*)&hin[(size_t)s1 * F_MID + ch];
        f16x4 v2 = *(const f16x4*)&hin[(size_t)s2 * F_MID + ch];
        f16x4 v3 = *(const f16x4*)&hin[(size_t)s3 * F_MID + ch];
        if (SCALED_IN) {
            acc += __builtin_convertvector(v0, f32x4) + __builtin_convertvector(v1, f32x4)
                 + __builtin_convertvector(v2, f32x4) + __builtin_convertvector(v3, f32x4);
        } else {
            acc += dinv[s0] * __builtin_convertvector(v0, f32x4)
                 + dinv[s1] * __builtin_convertvector(v1, f32x4)
                 + dinv[s2] * __builtin_convertvector(v2, f32x4)
                 + dinv[s3] * __builtin_convertvector(v3, f32x4);
        }
    }
    for (; k < cnt; ++k) {
        const int s = csr[start + k];
        f32x4 v = __builtin_convertvector(*(const f16x4*)&hin[(size_t)s * F_MID + ch], f32x4);
        acc += SCALED_IN ? v : dinv[s] * v;
    }
    acc *= di;

    if (POST) {
        const unsigned f0 = (unsigned)row * F_MID + (unsigned)ch;
        #pragma unroll
        for (int j = 0; j < 4; ++j) {
            float t = acc[j] + bias[ch + j];
            t = fmaxf(t, 0.0f);
            t = keep_mask(f0 + j) ? t * 2.0f : 0.0f;
            acc[j] = t * di;
        }
    }
    const int oc = SWZ ? (ch ^ ((row & 7) << 3)) : ch;
    *(f16x4*)&hout[(size_t)row * F_MID + oc] = __builtin_convertvector(acc, f16x4);
}

// ---------------- launch ----------------
extern "C" void kernel_launch(void* const* d_in, const int* in_sizes, int n_in,
                              void* d_out, int out_size, void* d_ws, size_t ws_size,
                              hipStream_t stream) {
    const float* x  = (const float*)d_in[0];
    const int*   ei = (const int*)d_in[1];
    const float* W1 = (const float*)d_in[2];
    const float* b1 = (const float*)d_in[3];
    const float* W2 = (const float*)d_in[4];
    const float* b2 = (const float*)d_in[5];
    float* out = (float*)d_out;

    // d_out doubles as fp16 scratch (dead before the final f32 overwrite):
    f16* h0 = (f16*)out;                               // [N,256] xW1, unscaled, linear
    f16* h1s = h0 + (size_t)N_NODES * F_MID;           // [N,256] post relu/dropout, dinv-scaled, linear

    // workspace
    f16*   h2agg = (f16*)d_ws;                         // [N,256] agg2 out, row-swizzled (GEMM2 A, glds)
    f16*   W1T   = h2agg + (size_t)(N_NODES + 64) * F_MID;  // [256][1024] swizzled
    f16*   W2T   = W1T + (size_t)F_MID * F_IN;         // [1024][256] swizzled
    float* dinv  = (float*)(W2T + (size_t)F_IN * F_MID);
    int*   deg   = (int*)(dinv + N_NODES);
    int*   rowst = deg + N_NODES;
    int*   cursor= rowst + N_NODES;
    int*   csr   = cursor + N_NODES;
    int*   counter = csr + N_EDGES;
    int*   flag    = counter + 1;

    // 1) prep: zero counters, dtype detect, W1 -> W1T (swizzled)
    k_prep<<<256, 256, 0, stream>>>(W1, W1T, ei, deg, cursor, counter, flag);

    // 2) GEMM1 (+riders: edge-degree count, W2 -> W2T): h0 = x @ W1.  BK=128, 8 steps.
    {
        const int mainx = (N_NODES + 63) / 64;         // 782
        dim3 grid(mainx + 242, 1);                     // 1024 blocks
        k_mfma<64, 256, 512, 1024, 128, false, true><<<grid, 512, 0, stream>>>(
            (const void*)x, W1T, (void*)h0, nullptr, N_NODES, F_MID,
            mainx, ei, deg, flag, W2, W2T);
    }

    // 3) rows (dinv, rowst), 4) fill (csr)
    k_rows<<<(N_NODES + 255) / 256, 256, 0, stream>>>(deg, dinv, rowst, counter);
    k_fill<<<(N_EDGES + 255) / 256, 256, 0, stream>>>(ei, rowst, cursor, csr, flag);

    // 5) agg1: dinv-weighted gather; +b1, relu, dropout, pre-scale.  6) agg2: swizzled out.
    k_agg16<1, 0, 0><<<N_NODES / 4, 256, 0, stream>>>(h0, h1s, csr, rowst, deg, dinv, b1);
    k_agg16<0, 1, 1><<<N_NODES / 4, 256, 0, stream>>>(h1s, h2agg, csr, rowst, deg, dinv, nullptr);

    // 7) GEMM2: out = h2agg @ W2 + b2.  Full-K A panel, BK=64, 4 steps.  grid (782,4).
    {
        const int mainx = (N_NODES + 63) / 64;
        dim3 grid(mainx, 4);
        k_mfma<64, 256, 512, 256, 64, true, false><<<grid, 512, 0, stream>>>(
            (const void*)h2agg, W2T, (void*)out, b2, N_NODES, F_IN,
            mainx, ei, deg, flag, W2, W2T);
    }
}